// Round 8
// baseline (127.606 us; speedup 1.0000x reference)
//
#include <hip/hip_runtime.h>
#include <hip/hip_bf16.h>
#include <math.h>

#define NROWS 4096
#define DDIM  512
#define BM    128
#define BK    32
#define NT    (DDIM / BK)              // 16 K-steps
#define NBLK  (NROWS / BM)             // 32
#define NTRI  (NBLK * (NBLK + 1) / 2)  // 528 upper-triangle tiles (528 % 8 == 0)

static constexpr float ALPHA = 10.0f;
static constexpr float BETA  = 2.0f;
static constexpr float BASE  = 0.5f;

typedef short bf16x8 __attribute__((ext_vector_type(8)));
typedef float f32x4 __attribute__((ext_vector_type(4)));

// ---- sortable-uint encoding for float atomic min/max ----
__device__ __forceinline__ unsigned enc_f32(float f) {
  unsigned b = __float_as_uint(f);
  return (b & 0x80000000u) ? ~b : (b | 0x80000000u);
}
__device__ __forceinline__ float dec_f32(unsigned u) {
  unsigned b = (u & 0x80000000u) ? (u & 0x7fffffffu) : ~u;
  return __uint_as_float(b);
}
__device__ __forceinline__ unsigned f2bf(float f) {
  __hip_bfloat16 h = __float2bfloat16(f);  // RNE
  return (unsigned)*reinterpret_cast<unsigned short*>(&h);
}
__device__ __forceinline__ float bf2f(unsigned short u) {
  return __uint_as_float(((unsigned)u) << 16);
}

#define GLOAD_LDS16(g, l)                                              \
  __builtin_amdgcn_global_load_lds(                                    \
      (const __attribute__((address_space(1))) void*)(g),              \
      (__attribute__((address_space(3))) void*)(l), 16, 0, 0)

// ---- convert X f32 -> bf16 packed (wave-per-row) + init min/max ----
__global__ __launch_bounds__(256) void convert_k(const float* __restrict__ X,
                                                 unsigned short* __restrict__ Xb,
                                                 unsigned* __restrict__ minb,
                                                 unsigned* __restrict__ maxb) {
  const int gid = blockIdx.x * 256 + threadIdx.x;
  if (gid < NROWS) {
    minb[gid] = 0xFF800000u;  // enc(+inf)
    maxb[gid] = 0x007FFFFFu;  // enc(-inf)
  }
  const int wid = threadIdx.x >> 6, lane = threadIdx.x & 63;
  const int r = blockIdx.x * 4 + wid;
  const size_t base = (size_t)r * DDIM + lane * 8;
  const float4 v0 = *reinterpret_cast<const float4*>(X + base);
  const float4 v1 = *reinterpret_cast<const float4*>(X + base + 4);
  uint4 u;
  u.x = f2bf(v0.x) | (f2bf(v0.y) << 16);
  u.y = f2bf(v0.z) | (f2bf(v0.w) << 16);
  u.z = f2bf(v1.x) | (f2bf(v1.y) << 16);
  u.w = f2bf(v1.z) | (f2bf(v1.w) << 16);
  *reinterpret_cast<uint4*>(Xb + base) = u;
}

// ---- triangle 128x128 MFMA GEMM, 2-phase prefetch (dbuf BK=32),
//      epilogue: min(pos)/max(neg) atomics + coalesced bf16 stores of both
//      orientations via LDS transpose. Diag elements treated/stored as 1.0. ----
__global__ __launch_bounds__(256) void gemm_tri_store(
    const unsigned short* __restrict__ Xb, const int* __restrict__ tgt,
    unsigned* __restrict__ minb, unsigned* __restrict__ maxb,
    unsigned short* __restrict__ simb) {
  __shared__ unsigned short lds[2][2][BM * BK] __attribute__((aligned(16)));  // 32 KB

  // XCD-bijective swizzle (528 % 8 == 0): consecutive tiles per XCD
  const int bswz = (blockIdx.x & 7) * (NTRI / 8) + (blockIdx.x >> 3);
  int kk0 = bswz, bi = 0;
  while (kk0 >= NBLK - bi) { kk0 -= NBLK - bi; ++bi; }
  const int bj = bi + kk0;
  const int i0 = bi * BM, j0 = bj * BM;
  const bool diagb = (bi == bj);

  const int tid = threadIdx.x;
  const int w = tid >> 6, lane = tid & 63;
  const int wr = w >> 1, wc = w & 1;
  const int g = lane >> 4, q = lane & 15;
  const char* Xbb = (const char*)Xb;

  f32x4 acc[4][4];
  #pragma unroll
  for (int m = 0; m < 4; ++m)
    #pragma unroll
    for (int n = 0; n < 4; ++n) acc[m][n] = (f32x4)0.0f;

  // stage tile t into dbuf 'buf' (A panel; B panel only when off-diag)
  #define STAGE(buf, t)                                                        \
    do {                                                                       \
      const int kb_ = (t) * (BK * 2);                                          \
      _Pragma("unroll")                                                        \
      for (int l_ = 0; l_ < 2; ++l_) {                                         \
        const int lin_ = (l_ * 256 + tid) * 16;                                \
        const int row_ = lin_ >> 6;                                            \
        const int col_ = lin_ & 63;                                            \
        GLOAD_LDS16(Xbb + (size_t)(i0 + row_) * (DDIM * 2) + kb_ + col_,       \
                    (char*)&lds[buf][0][0] + lin_);                            \
        if (!diagb)                                                            \
          GLOAD_LDS16(Xbb + (size_t)(j0 + row_) * (DDIM * 2) + kb_ + col_,     \
                      (char*)&lds[buf][1][0] + lin_);                          \
      }                                                                        \
    } while (0)

  STAGE(0, 0);
  __syncthreads();  // prologue tile landed
  int cur = 0;
  for (int t = 0; t < NT; ++t) {
    if (t + 1 < NT) STAGE(cur ^ 1, t + 1);  // issue next-tile loads first
    const char* Ab = (const char*)&lds[cur][0][0];
    const char* Bb = diagb ? Ab : (const char*)&lds[cur][1][0];
    bf16x8 a[4], b[4];
    #pragma unroll
    for (int fm = 0; fm < 4; ++fm)
      a[fm] = *reinterpret_cast<const bf16x8*>(Ab + (wr * 64 + fm * 16 + q) * 64 + g * 16);
    #pragma unroll
    for (int fn = 0; fn < 4; ++fn)
      b[fn] = *reinterpret_cast<const bf16x8*>(Bb + (wc * 64 + fn * 16 + q) * 64 + g * 16);
    #pragma unroll
    for (int fm = 0; fm < 4; ++fm)
      #pragma unroll
      for (int fn = 0; fn < 4; ++fn)
        acc[fm][fn] = __builtin_amdgcn_mfma_f32_16x16x32_bf16(a[fm], b[fn], acc[fm][fn], 0, 0, 0);
    __syncthreads();  // drains vmcnt(0): next buffer staged; current reads done
    cur ^= 1;
  }

  // ---- epilogue part 1: min(pos)/max(neg) atomics (R2/R4-verified) ----
  const int rbase = i0 + wr * 64;
  int cg[4], tj[4], cloc[4];
  #pragma unroll
  for (int fn = 0; fn < 4; ++fn) {
    cloc[fn] = wc * 64 + fn * 16 + q;
    cg[fn] = j0 + cloc[fn];
    tj[fn] = tgt[cg[fn]];
  }
  int ti16[16];
  #pragma unroll
  for (int fm = 0; fm < 4; ++fm)
    #pragma unroll
    for (int reg = 0; reg < 4; ++reg)
      ti16[fm * 4 + reg] = tgt[rbase + fm * 16 + g * 4 + reg];

  #pragma unroll
  for (int fm = 0; fm < 4; ++fm) {
    #pragma unroll
    for (int reg = 0; reg < 4; ++reg) {
      const int rloc = wr * 64 + fm * 16 + g * 4 + reg;
      const int r = i0 + rloc;
      const int tr = ti16[fm * 4 + reg];
      float mnp = INFINITY, mxn = -INFINITY;
      #pragma unroll
      for (int fn = 0; fn < 4; ++fn) {
        float s = acc[fm][fn][reg];
        if (diagb && rloc == cloc[fn]) s = 1.0f;  // diag: excluded by s<1.0
        if (tj[fn] == tr) {
          if (s < 1.0f) mnp = fminf(mnp, s);
        } else {
          mxn = fmaxf(mxn, s);
        }
      }
      #pragma unroll
      for (int off = 1; off < 16; off <<= 1) {
        mnp = fminf(mnp, __shfl_xor(mnp, off));
        mxn = fmaxf(mxn, __shfl_xor(mxn, off));
      }
      if (q == 0) {
        if (mnp != INFINITY) atomicMin(minb + r, enc_f32(mnp));
        if (mxn != -INFINITY) atomicMax(maxb + r, enc_f32(mxn));
      }
    }
  }
  if (!diagb) {  // col-side
    #pragma unroll
    for (int fn = 0; fn < 4; ++fn) {
      const int tc = tj[fn];
      float mnp = INFINITY, mxn = -INFINITY;
      #pragma unroll
      for (int fm = 0; fm < 4; ++fm)
        #pragma unroll
        for (int reg = 0; reg < 4; ++reg) {
          const float s = acc[fm][fn][reg];
          if (ti16[fm * 4 + reg] == tc) {
            if (s < 1.0f) mnp = fminf(mnp, s);
          } else {
            mxn = fmaxf(mxn, s);
          }
        }
      mnp = fminf(mnp, __shfl_xor(mnp, 16));
      mnp = fminf(mnp, __shfl_xor(mnp, 32));
      mxn = fmaxf(mxn, __shfl_xor(mxn, 16));
      mxn = fmaxf(mxn, __shfl_xor(mxn, 32));
      if (lane < 16) {
        if (mnp != INFINITY) atomicMin(minb + cg[fn], enc_f32(mnp));
        if (mxn != -INFINITY) atomicMax(maxb + cg[fn], enc_f32(mxn));
      }
    }
  }

  // ---- epilogue part 2: coalesced stores via LDS transpose (R7-verified) ----
  // staging view: 32 rows x 136 ushort (8704 B, fits in lds[0] region; dead)
  unsigned short* SV = &lds[0][0][0];
  __syncthreads();
  #pragma unroll
  for (int orient = 0; orient < 2; ++orient) {
    if (orient == 1 && diagb) break;
    for (int d = 0; d < 4; ++d) {
      if (orient == 0) {
        if (wr == (d >> 1)) {
          #pragma unroll
          for (int h = 0; h < 2; ++h) {
            const int fm = 2 * (d & 1) + h;
            #pragma unroll
            for (int fn = 0; fn < 4; ++fn)
              #pragma unroll
              for (int reg = 0; reg < 4; ++reg) {
                const int shrow = h * 16 + g * 4 + reg;
                const int col = wc * 64 + fn * 16 + q;
                unsigned short v = (unsigned short)f2bf(acc[fm][fn][reg]);
                if (diagb && (32 * d + shrow == col)) v = 0x3F80;  // diag = 1.0
                SV[shrow * 136 + col] = v;
              }
          }
        }
      } else {
        if (wc == (d >> 1)) {
          #pragma unroll
          for (int h = 0; h < 2; ++h) {
            const int fn = 2 * (d & 1) + h;
            const int shrow = h * 16 + q;
            #pragma unroll
            for (int fm = 0; fm < 4; ++fm) {
              const int colR = wr * 64 + fm * 16 + g * 4;
              uint2 uu;
              uu.x = f2bf(acc[fm][fn][0]) | (f2bf(acc[fm][fn][1]) << 16);
              uu.y = f2bf(acc[fm][fn][2]) | (f2bf(acc[fm][fn][3]) << 16);
              *reinterpret_cast<uint2*>(&SV[shrow * 136 + colR]) = uu;
            }
          }
        }
      }
      __syncthreads();
      #pragma unroll
      for (int rr = 0; rr < 2; ++rr) {
        const int s = tid + rr * 256;
        const int row = s >> 4, cs = s & 15;
        const bf16x8 vv = *reinterpret_cast<const bf16x8*>(&SV[row * 136 + cs * 8]);
        unsigned short* dst =
            (orient == 0)
                ? simb + (size_t)(i0 + d * 32 + row) * NROWS + j0 + cs * 8
                : simb + (size_t)(j0 + d * 32 + row) * NROWS + i0 + cs * 8;
        *reinterpret_cast<bf16x8*>(dst) = vv;
      }
      __syncthreads();
    }
  }
}

// ---- wave-per-row, single phase: stream row, exp-sums + last-row stats ----
__global__ __launch_bounds__(256) void rows_k(
    const unsigned short* __restrict__ simb, const int* __restrict__ tgt,
    const unsigned* __restrict__ minb, const unsigned* __restrict__ maxb,
    const float* __restrict__ marginp, float* __restrict__ rowloss,
    float* __restrict__ rowvalid, float* __restrict__ lacc) {
  __shared__ int tgl[NROWS];  // 16 KB
  const int tid = threadIdx.x;
  #pragma unroll
  for (int c = 0; c < 4; ++c)
    reinterpret_cast<int4*>(tgl)[tid + c * 256] =
        reinterpret_cast<const int4*>(tgt)[tid + c * 256];
  __syncthreads();

  const int wid = tid >> 6, lane = tid & 63;
  const int i = blockIdx.x * 4 + wid;
  const int ti = tgl[i];
  const float minp = dec_f32(minb[i]);
  const float maxn = dec_f32(maxb[i]);
  const float margin = *marginp;
  const unsigned short* row = simb + (size_t)i * NROWS;
  const bool lastw = (i == NROWS - 1);

  float psum = 0.0f, nsum = 0.0f;
  float lsp = 0.0f, lcp = 0.0f, lsn = 0.0f, lcn = 0.0f;
  #pragma unroll
  for (int c = 0; c < 8; ++c) {
    const int j0 = c * 512 + lane * 8;
    const bf16x8 v = *reinterpret_cast<const bf16x8*>(row + j0);
    const int4 t0 = *reinterpret_cast<const int4*>(tgl + j0);
    const int4 t1 = *reinterpret_cast<const int4*>(tgl + j0 + 4);
    const int tj[8] = {t0.x, t0.y, t0.z, t0.w, t1.x, t1.y, t1.z, t1.w};
    #pragma unroll
    for (int e = 0; e < 8; ++e) {
      const float s = bf2f((unsigned short)v[e]);
      if (tj[e] != ti) {
        if (s + margin - minp > 0.0f) nsum += __expf(ALPHA * (s - BASE));
        if (lastw) { lsn += s; lcn += 1.0f; }
      } else if (s < 1.0f) {
        if (maxn - s + margin > 0.0f) psum += __expf(-BETA * (s - BASE));
        if (lastw) { lsp += s; lcp += 1.0f; }
      }
    }
  }
  #pragma unroll
  for (int off = 1; off < 64; off <<= 1) {
    psum += __shfl_xor(psum, off);
    nsum += __shfl_xor(nsum, off);
  }
  if (lastw) {
    #pragma unroll
    for (int off = 1; off < 64; off <<= 1) {
      lsp += __shfl_xor(lsp, off); lcp += __shfl_xor(lcp, off);
      lsn += __shfl_xor(lsn, off); lcn += __shfl_xor(lcn, off);
    }
  }
  if (lane == 0) {
    const bool valid = (psum > 0.0f) && (nsum > 0.0f);
    rowloss[i] = valid ? (2.0f / BETA) * log1pf(psum) + (2.0f / ALPHA) * log1pf(nsum) : 0.0f;
    rowvalid[i] = valid ? 0.0f : 1.0f;
    if (lastw) { lacc[0] = lsp; lacc[1] = lcp; lacc[2] = lsn; lacc[3] = lcn; }
  }
}

__device__ __forceinline__ float block_sum(float v) {
  __shared__ float sh[4];
  #pragma unroll
  for (int off = 32; off > 0; off >>= 1) v += __shfl_down(v, off);
  if ((threadIdx.x & 63) == 0) sh[threadIdx.x >> 6] = v;
  __syncthreads();
  float r = sh[0] + sh[1] + sh[2] + sh[3];
  __syncthreads();
  return r;
}

__global__ __launch_bounds__(256) void finalize_k(
    const float* __restrict__ rowloss, const float* __restrict__ rowvalid,
    const float* __restrict__ lacc, float* __restrict__ out) {
  float lsum = 0.0f, inval = 0.0f;
  #pragma unroll
  for (int c = 0; c < 16; ++c) {
    const int i = c * 256 + threadIdx.x;
    lsum += rowloss[i];
    inval += rowvalid[i];
  }
  lsum = block_sum(lsum);
  inval = block_sum(inval);
  if (threadIdx.x == 0) {
    out[0] = lsum / (float)NROWS;
    out[1] = inval / (float)NROWS;
    out[2] = lacc[0] / fmaxf(lacc[1], 1.0f);
    out[3] = lacc[2] / fmaxf(lacc[3], 1.0f);
  }
}

extern "C" void kernel_launch(void* const* d_in, const int* in_sizes, int n_in,
                              void* d_out, int out_size, void* d_ws, size_t ws_size,
                              hipStream_t stream) {
  const float* X = (const float*)d_in[0];
  const int* tgt = (const int*)d_in[1];
  const float* marginp = (const float*)d_in[2];
  float* out = (float*)d_out;

  char* ws = (char*)d_ws;
  float* rowloss = (float*)ws;                    // @0     16 KB
  float* rowvalid = (float*)(ws + (16 << 10));    // @16K   16 KB
  float* lacc = (float*)(ws + (32 << 10));        // @32K   small
  unsigned* minb = (unsigned*)(ws + (48 << 10));  // @48K   16 KB
  unsigned* maxb = (unsigned*)(ws + (64 << 10));  // @64K   16 KB
  unsigned short* Xb = (unsigned short*)(ws + (128 << 10));  // 4 MB
  unsigned short* simb = (unsigned short*)(ws + (128 << 10) + ((size_t)4 << 20));  // 32 MB

  convert_k<<<dim3(NROWS / 4), 256, 0, stream>>>(X, Xb, minb, maxb);
  gemm_tri_store<<<dim3(NTRI), 256, 0, stream>>>(Xb, tgt, minb, maxb, simb);
  rows_k<<<dim3(NROWS / 4), 256, 0, stream>>>(simb, tgt, minb, maxb, marginp,
                                              rowloss, rowvalid, lacc);
  finalize_k<<<dim3(1), 256, 0, stream>>>(rowloss, rowvalid, lacc, out);
}